// Round 14
// baseline (354.279 us; speedup 1.0000x reference)
//
#include <hip/hip_runtime.h>

#define BN 512            // matrix dimension n
#define NW 16             // waves per block (1024 threads)
#define RPW 32            // rows per wave
#define LR  9             // rows per wave kept resident in LDS

static constexpr float kScale = 28.853900817779268f;   // log2(e)/tau

__device__ __forceinline__ float fexp2(float x){ return __builtin_amdgcn_exp2f(x); }
__device__ __forceinline__ float flog2(float x){ return __builtin_amdgcn_logf(x); }
__device__ __forceinline__ float frcp (float x){ return __builtin_amdgcn_rcpf(x); }

// ---- DPP 64-lane reductions (proven R11) ----
__device__ __forceinline__ float dpp_sum64(float s){
    int t;
    t = __builtin_amdgcn_update_dpp(0, __float_as_int(s), 0x111, 0xf, 0xf, true); s += __int_as_float(t);
    t = __builtin_amdgcn_update_dpp(0, __float_as_int(s), 0x112, 0xf, 0xf, true); s += __int_as_float(t);
    t = __builtin_amdgcn_update_dpp(0, __float_as_int(s), 0x114, 0xf, 0xf, true); s += __int_as_float(t);
    t = __builtin_amdgcn_update_dpp(0, __float_as_int(s), 0x118, 0xf, 0xf, true); s += __int_as_float(t);
    t = __builtin_amdgcn_update_dpp(0, __float_as_int(s), 0x142, 0xa, 0xf, true); s += __int_as_float(t);
    t = __builtin_amdgcn_update_dpp(0, __float_as_int(s), 0x143, 0xc, 0xf, true); s += __int_as_float(t);
    return __int_as_float(__builtin_amdgcn_readlane(__float_as_int(s), 63));
}
__device__ __forceinline__ float dpp_max64(float m){
    const int NI = __float_as_int(-__builtin_inff());
    int t;
    t = __builtin_amdgcn_update_dpp(NI, __float_as_int(m), 0x111, 0xf, 0xf, false); m = fmaxf(m, __int_as_float(t));
    t = __builtin_amdgcn_update_dpp(NI, __float_as_int(m), 0x112, 0xf, 0xf, false); m = fmaxf(m, __int_as_float(t));
    t = __builtin_amdgcn_update_dpp(NI, __float_as_int(m), 0x114, 0xf, 0xf, false); m = fmaxf(m, __int_as_float(t));
    t = __builtin_amdgcn_update_dpp(NI, __float_as_int(m), 0x118, 0xf, 0xf, false); m = fmaxf(m, __int_as_float(t));
    t = __builtin_amdgcn_update_dpp(NI, __float_as_int(m), 0x142, 0xa, 0xf, false); m = fmaxf(m, __int_as_float(t));
    t = __builtin_amdgcn_update_dpp(NI, __float_as_int(m), 0x143, 0xc, 0xf, false); m = fmaxf(m, __int_as_float(t));
    return __int_as_float(__builtin_amdgcn_readlane(__float_as_int(m), 63));
}

// round-to-nearest-even f32->bf16, pack two into u32 (a=lo16, b=hi16)
__device__ __forceinline__ unsigned rtne_pack(float a, float b){
    unsigned ua = __float_as_uint(a), ub = __float_as_uint(b);
    unsigned lo = (ua + 0x7fffu + ((ua >> 16) & 1u)) >> 16;
    unsigned hi = (ub + 0x7fffu + ((ub >> 16) & 1u)) & 0xffff0000u;
    return lo | hi;
}
__device__ __forceinline__ void unpack2(unsigned w, float& lo, float& hi){
    lo = __uint_as_float(w << 16);
    hi = __uint_as_float(w & 0xffff0000u);
}

// (1024,1): the ONLY empirically non-spilling config. Allocator pins 16-wave
// blocks at 64 VGPRs -> kernel must FIT ~64 VGPRs.
__global__ __launch_bounds__(1024, 1) void sinkhorn_fused(
    const float* __restrict__ logits, float* __restrict__ out,
    unsigned short* __restrict__ ws, int use_ws)
{
    __shared__ float Bf[BN];                       // linear col factor (2 KB)
    __shared__ float SL[BN];                       // latest row sums (2 KB)
    __shared__ float Cn[BN];                       // atomic col accumulation (2 KB)
    __shared__ unsigned short Mlds[NW * LR * BN];  // LDS-resident M rows (147,456 B)

    const int b = blockIdx.x;
    const size_t base = (size_t)b * BN * BN;
    const float* __restrict__ Zb = logits + base;
    float* __restrict__ Ob = out + base;
    unsigned short* __restrict__ Mb = use_ws ? (ws + base) : (unsigned short*)Ob;

    const int tid  = threadIdx.x;
    const int lane = tid & 63;
    const int wave = tid >> 6;
    const int wb   = wave * RPW;

    if (tid < BN) Cn[tid] = 0.0f;
    __syncthreads();

    // bank-rotated LDS atomic col accumulation: per instruction, lanes l and l+32
    // share a bank (2-way = free, m136); all 512 addresses distinct per wave.
#define COL_ATOMIC(ca)                                                             \
    {                                                                              \
        _Pragma("unroll")                                                          \
        for (int k = 0; k < 8; ++k) {                                              \
            const int idx = ((lane >> 2) + k) & 7;                                 \
            atomicAdd(&Cn[8 * lane + idx], (ca)[idx]);                             \
        }                                                                          \
    }

    // ---------------- pass 0: fp32 read, exact row LSE, M = bf16(2^(t-m-lg2s+64)) ----------------
    {
        float ca[8] = {0.f,0.f,0.f,0.f,0.f,0.f,0.f,0.f};

        #pragma unroll 2
        for (int r = 0; r < RPW; ++r) {
            const int i = wb + r;
            const float4 x0 = *reinterpret_cast<const float4*>(Zb + (size_t)i * BN + 4 * lane);
            const float4 x1 = *reinterpret_cast<const float4*>(Zb + (size_t)i * BN + 256 + 4 * lane);

            float t[8];
            t[0] = x0.x * kScale; t[1] = x0.y * kScale; t[2] = x0.z * kScale; t[3] = x0.w * kScale;
            t[4] = x1.x * kScale; t[5] = x1.y * kScale; t[6] = x1.z * kScale; t[7] = x1.w * kScale;

            float m = t[0];
            #pragma unroll
            for (int k = 1; k < 8; ++k) m = fmaxf(m, t[k]);
            m = dpp_max64(m);

            float p[8], s = 0.f;
            #pragma unroll
            for (int k = 0; k < 8; ++k) { p[k] = fexp2(t[k] - m); s += p[k]; }
            s = dpp_sum64(s);

            const float f = fexp2(64.0f - flog2(s));   // 2^64 / s
            float Mv[8];
            #pragma unroll
            for (int k = 0; k < 8; ++k) { Mv[k] = p[k] * f; ca[k] += Mv[k]; }

            int4 packed;
            packed.x = (int)rtne_pack(Mv[0], Mv[1]);
            packed.y = (int)rtne_pack(Mv[2], Mv[3]);
            packed.z = (int)rtne_pack(Mv[4], Mv[5]);
            packed.w = (int)rtne_pack(Mv[6], Mv[7]);
            if (r < LR)
                *reinterpret_cast<int4*>(&Mlds[(wave * LR + r) * BN + lane * 8]) = packed;
            else
                *reinterpret_cast<int4*>(Mb + (size_t)i * BN + lane * 8) = packed;
        }

        COL_ATOMIC(ca);
        __syncthreads();                 // drains M writes + atomics
    }

    // per-wave global M base (rows LR..31 only)
    const unsigned short* Mw = Mb + (size_t)wb * BN + lane * 8;
#define LD(r)  (*reinterpret_cast<const int4*>(Mw + (size_t)(r) * BN))
#define LDL(r) (*reinterpret_cast<const int4*>(&Mlds[(wave * LR + (r)) * BN + lane * 8]))

    // prefetch pass-1 global rows 9..12 (live across the barrier)
    int4 W0 = LD(9), W1 = LD(10), W2 = LD(11), W3 = LD(12);

    if (tid < BN) { Bf[tid] = frcp(Cn[tid]); Cn[tid] = 0.0f; }
    __syncthreads();

#define STEP1(ridx, W)                                                             \
    {                                                                              \
        float e[8];                                                                \
        unpack2((unsigned)(W).x, e[0], e[1]); unpack2((unsigned)(W).y, e[2], e[3]); \
        unpack2((unsigned)(W).z, e[4], e[5]); unpack2((unsigned)(W).w, e[6], e[7]); \
        float a0 = 0.f, a1 = 0.f, a2 = 0.f, a3 = 0.f;                              \
        a0 = fmaf(e[0], bl[0], a0); a1 = fmaf(e[1], bl[1], a1);                    \
        a2 = fmaf(e[2], bl[2], a2); a3 = fmaf(e[3], bl[3], a3);                    \
        a0 = fmaf(e[4], bl[4], a0); a1 = fmaf(e[5], bl[5], a1);                    \
        a2 = fmaf(e[6], bl[6], a2); a3 = fmaf(e[7], bl[7], a3);                    \
        const float s = dpp_sum64((a0 + a1) + (a2 + a3));                          \
        const float A = frcp(s);                                                   \
        if (lane == 0) SL[wb + (ridx)] = s;                                        \
        _Pragma("unroll")                                                          \
        for (int k = 0; k < 8; ++k) ca[k] = fmaf(e[k], A, ca[k]);                  \
    }

    // ---------------- passes 1..9: rows 0..8 from LDS, 9..31 depth-4 global ----------------
    for (int it = 1; it < 10; ++it) {
        float bl[8];
        #pragma unroll
        for (int k = 0; k < 8; ++k) bl[k] = Bf[8 * lane + k];
        float ca[8] = {0.f,0.f,0.f,0.f,0.f,0.f,0.f,0.f};

        // LDS-resident rows 0..8 (V0/V1 ping-pong, row order preserved)
        {
            int4 V0 = LDL(0), V1 = LDL(1);
            STEP1(0, V0); V0 = LDL(2);
            STEP1(1, V1); V1 = LDL(3);
            STEP1(2, V0); V0 = LDL(4);
            STEP1(3, V1); V1 = LDL(5);
            STEP1(4, V0); V0 = LDL(6);
            STEP1(5, V1); V1 = LDL(7);
            STEP1(6, V0); V0 = LDL(8);
            STEP1(7, V1);
            STEP1(8, V0);
        }

        // global rows 9..24 (4 groups of 4), loads run 4 rows ahead
        #pragma unroll 1
        for (int g = 0; g < 16; g += 4) {
            STEP1(9 + g,  W0); W0 = LD(13 + g);
            STEP1(10 + g, W1); W1 = LD(14 + g);
            STEP1(11 + g, W2); W2 = LD(15 + g);
            STEP1(12 + g, W3); W3 = LD(16 + g);
        }
        // rows 25..27 reload the last three rows
        STEP1(25, W0); W0 = LD(29);
        STEP1(26, W1); W1 = LD(30);
        STEP1(27, W2); W2 = LD(31);
        // rows 28..31 consume-only (pipeline drains)
        STEP1(28, W3);
        STEP1(29, W0);
        STEP1(30, W1);
        STEP1(31, W2);
        // next-pass prefetch, issued before the barriers (crosses them in flight)
        if (it != 9) { W0 = LD(9); W1 = LD(10); W2 = LD(11); W3 = LD(12); }

        COL_ATOMIC(ca);
        __syncthreads();
        if (tid < BN) { Bf[tid] = frcp(Cn[tid]); Cn[tid] = 0.0f; }
        __syncthreads();
    }

    // ---------------- final: out = M * A_i * B_j (M from LDS for local rows) ----------------
    {
        float bf[8];
        #pragma unroll
        for (int k = 0; k < 8; ++k) bf[k] = Bf[8 * lane + k];

        auto emit_row = [&](int j) {
            const int lr = j & 31;
            const int4 w = (lr < LR)
                ? *reinterpret_cast<const int4*>(&Mlds[((j >> 5) * LR + lr) * BN + lane * 8])
                : *reinterpret_cast<const int4*>(Mb + (size_t)j * BN + lane * 8);
            float e[8];
            unpack2((unsigned)w.x, e[0], e[1]); unpack2((unsigned)w.y, e[2], e[3]);
            unpack2((unsigned)w.z, e[4], e[5]); unpack2((unsigned)w.w, e[6], e[7]);
            const float A = frcp(SL[j]);
            float4 o0, o1;
            o0.x = e[0] * A * bf[0]; o0.y = e[1] * A * bf[1];
            o0.z = e[2] * A * bf[2]; o0.w = e[3] * A * bf[3];
            o1.x = e[4] * A * bf[4]; o1.y = e[5] * A * bf[5];
            o1.z = e[6] * A * bf[6]; o1.w = e[7] * A * bf[7];
            *reinterpret_cast<float4*>(Ob + (size_t)j * BN + 4 * lane) = o0;
            *reinterpret_cast<float4*>(Ob + (size_t)j * BN + 256 + 4 * lane) = o1;
        };

        if (use_ws) {
            #pragma unroll 2
            for (int r = 0; r < RPW; ++r) emit_row(wb + r);
        } else {
            // M aliases out: descending power-of-2 ranges; fp32 write of row j clobbers
            // M rows 2j,2j+1, always in an already-consumed (higher) range.
            // (LDS-resident rows are immune to the aliasing entirely.)
            for (int L = 256; L >= 1; L >>= 1) {
                for (int j = L + wave; j < 2 * L; j += NW) emit_row(j);
                __syncthreads();
            }
            if (wave == 0) emit_row(0);
        }
    }
#undef LD
#undef LDL
#undef STEP1
#undef COL_ATOMIC
}

extern "C" void kernel_launch(void* const* d_in, const int* in_sizes, int n_in,
                              void* d_out, int out_size, void* d_ws, size_t ws_size,
                              hipStream_t stream) {
    const float* logits = (const float*)d_in[0];
    float* out = (float*)d_out;
    const int B = in_sizes[0] / (BN * BN);   // 256
    const size_t need = (size_t)B * BN * BN * sizeof(unsigned short);  // 128 MB
    const int use_ws = (ws_size >= need) ? 1 : 0;
    hipLaunchKernelGGL(sinkhorn_fused, dim3(B), dim3(1024), 0, stream,
                       logits, out, (unsigned short*)d_ws, use_ws);
}

// Round 15
// 263.549 us; speedup vs baseline: 1.3443x; 1.3443x over previous
//
#include <hip/hip_runtime.h>

#define BN 512            // matrix dimension n
#define NW 16             // waves per block (1024 threads)
#define RPW 32            // rows per wave
#define LR  7             // rows per wave kept resident in LDS

static constexpr float kScale = 28.853900817779268f;   // log2(e)/tau

__device__ __forceinline__ float fexp2(float x){ return __builtin_amdgcn_exp2f(x); }
__device__ __forceinline__ float flog2(float x){ return __builtin_amdgcn_logf(x); }
__device__ __forceinline__ float frcp (float x){ return __builtin_amdgcn_rcpf(x); }

// ---- DPP 64-lane reductions (proven R11) ----
__device__ __forceinline__ float dpp_sum64(float s){
    int t;
    t = __builtin_amdgcn_update_dpp(0, __float_as_int(s), 0x111, 0xf, 0xf, true); s += __int_as_float(t);
    t = __builtin_amdgcn_update_dpp(0, __float_as_int(s), 0x112, 0xf, 0xf, true); s += __int_as_float(t);
    t = __builtin_amdgcn_update_dpp(0, __float_as_int(s), 0x114, 0xf, 0xf, true); s += __int_as_float(t);
    t = __builtin_amdgcn_update_dpp(0, __float_as_int(s), 0x118, 0xf, 0xf, true); s += __int_as_float(t);
    t = __builtin_amdgcn_update_dpp(0, __float_as_int(s), 0x142, 0xa, 0xf, true); s += __int_as_float(t);
    t = __builtin_amdgcn_update_dpp(0, __float_as_int(s), 0x143, 0xc, 0xf, true); s += __int_as_float(t);
    return __int_as_float(__builtin_amdgcn_readlane(__float_as_int(s), 63));
}
__device__ __forceinline__ float dpp_max64(float m){
    const int NI = __float_as_int(-__builtin_inff());
    int t;
    t = __builtin_amdgcn_update_dpp(NI, __float_as_int(m), 0x111, 0xf, 0xf, false); m = fmaxf(m, __int_as_float(t));
    t = __builtin_amdgcn_update_dpp(NI, __float_as_int(m), 0x112, 0xf, 0xf, false); m = fmaxf(m, __int_as_float(t));
    t = __builtin_amdgcn_update_dpp(NI, __float_as_int(m), 0x114, 0xf, 0xf, false); m = fmaxf(m, __int_as_float(t));
    t = __builtin_amdgcn_update_dpp(NI, __float_as_int(m), 0x118, 0xf, 0xf, false); m = fmaxf(m, __int_as_float(t));
    t = __builtin_amdgcn_update_dpp(NI, __float_as_int(m), 0x142, 0xa, 0xf, false); m = fmaxf(m, __int_as_float(t));
    t = __builtin_amdgcn_update_dpp(NI, __float_as_int(m), 0x143, 0xc, 0xf, false); m = fmaxf(m, __int_as_float(t));
    return __int_as_float(__builtin_amdgcn_readlane(__float_as_int(m), 63));
}

// round-to-nearest-even f32->bf16, pack two into u32 (a=lo16, b=hi16)
__device__ __forceinline__ unsigned rtne_pack(float a, float b){
    unsigned ua = __float_as_uint(a), ub = __float_as_uint(b);
    unsigned lo = (ua + 0x7fffu + ((ua >> 16) & 1u)) >> 16;
    unsigned hi = (ub + 0x7fffu + ((ub >> 16) & 1u)) & 0xffff0000u;
    return lo | hi;
}
__device__ __forceinline__ void unpack2(unsigned w, float& lo, float& hi){
    lo = __uint_as_float(w << 16);
    hi = __uint_as_float(w & 0xffff0000u);
}

// padded (stride-9, coprime with 32 banks) cred slot for position p in [0,512)
__device__ __forceinline__ int credIdx(int p){
    return ((p >> 8) * 288) + (((p & 255) >> 3) * 9) + (p & 7);
}

// (1024,1): the ONLY empirically non-spilling config. Allocator pins 16-wave
// blocks at 64 VGPRs -> kernel must FIT ~64 VGPRs. Deterministic cred reduce
// (R14's LDS atomics regressed 34%: 264 -> 354 us).
__global__ __launch_bounds__(1024, 1) void sinkhorn_fused(
    const float* __restrict__ logits, float* __restrict__ out,
    unsigned short* __restrict__ ws, int use_ws)
{
    __shared__ float Bf[BN];                       // linear col factor
    __shared__ float SL[BN];                       // latest row sums
    __shared__ float cred[NW][576];                // padded col partials (36,864 B)
    __shared__ unsigned short Mlds[NW * LR * BN];  // LDS-resident M rows (114,688 B)

    const int b = blockIdx.x;
    const size_t base = (size_t)b * BN * BN;
    const float* __restrict__ Zb = logits + base;
    float* __restrict__ Ob = out + base;
    unsigned short* __restrict__ Mb = use_ws ? (ws + base) : (unsigned short*)Ob;

    const int tid  = threadIdx.x;
    const int lane = tid & 63;
    const int wave = tid >> 6;
    const int wb   = wave * RPW;

    // ---------------- pass 0: fp32 read, exact row LSE, M = bf16(2^(t-m-lg2s+64)) ----------------
    {
        float ca[8] = {0.f,0.f,0.f,0.f,0.f,0.f,0.f,0.f};

        #pragma unroll 2
        for (int r = 0; r < RPW; ++r) {
            const int i = wb + r;
            const float4 x0 = *reinterpret_cast<const float4*>(Zb + (size_t)i * BN + 4 * lane);
            const float4 x1 = *reinterpret_cast<const float4*>(Zb + (size_t)i * BN + 256 + 4 * lane);

            float t[8];
            t[0] = x0.x * kScale; t[1] = x0.y * kScale; t[2] = x0.z * kScale; t[3] = x0.w * kScale;
            t[4] = x1.x * kScale; t[5] = x1.y * kScale; t[6] = x1.z * kScale; t[7] = x1.w * kScale;

            float m = t[0];
            #pragma unroll
            for (int k = 1; k < 8; ++k) m = fmaxf(m, t[k]);
            m = dpp_max64(m);

            float p[8], s = 0.f;
            #pragma unroll
            for (int k = 0; k < 8; ++k) { p[k] = fexp2(t[k] - m); s += p[k]; }
            s = dpp_sum64(s);

            const float f = fexp2(64.0f - flog2(s));   // 2^64 / s
            float Mv[8];
            #pragma unroll
            for (int k = 0; k < 8; ++k) { Mv[k] = p[k] * f; ca[k] += Mv[k]; }

            int4 packed;
            packed.x = (int)rtne_pack(Mv[0], Mv[1]);
            packed.y = (int)rtne_pack(Mv[2], Mv[3]);
            packed.z = (int)rtne_pack(Mv[4], Mv[5]);
            packed.w = (int)rtne_pack(Mv[6], Mv[7]);
            if (r < LR)
                *reinterpret_cast<int4*>(&Mlds[(wave * LR + r) * BN + lane * 8]) = packed;
            else
                *reinterpret_cast<int4*>(Mb + (size_t)i * BN + lane * 8) = packed;
        }

        const int cbase = (lane < 32) ? lane * 9 : 288 + (lane - 32) * 9;
        #pragma unroll
        for (int k = 0; k < 8; ++k) cred[wave][cbase + k] = ca[k];
        __syncthreads();                 // drains M global+LDS writes
    }

    // per-wave global M base (rows LR..31 only)
    const unsigned short* Mw = Mb + (size_t)wb * BN + lane * 8;
#define LD(r)  (*reinterpret_cast<const int4*>(Mw + (size_t)(r) * BN))
#define LDL(r) (*reinterpret_cast<const int4*>(&Mlds[(wave * LR + (r)) * BN + lane * 8]))

    // prefetch pass-1 global rows 7..10 (named regs, live across the barrier)
    int4 W0 = LD(7), W1 = LD(8), W2 = LD(9), W3 = LD(10);

    if (tid < BN) {
        const int ci = credIdx(tid);
        float s = 0.f;
        #pragma unroll
        for (int wv = 0; wv < NW; ++wv) s += cred[wv][ci];
        Bf[tid] = frcp(s);
    }
    __syncthreads();

#define STEP1(ridx, W)                                                             \
    {                                                                              \
        float e[8];                                                                \
        unpack2((unsigned)(W).x, e[0], e[1]); unpack2((unsigned)(W).y, e[2], e[3]); \
        unpack2((unsigned)(W).z, e[4], e[5]); unpack2((unsigned)(W).w, e[6], e[7]); \
        float a0 = 0.f, a1 = 0.f, a2 = 0.f, a3 = 0.f;                              \
        a0 = fmaf(e[0], bl[0], a0); a1 = fmaf(e[1], bl[1], a1);                    \
        a2 = fmaf(e[2], bl[2], a2); a3 = fmaf(e[3], bl[3], a3);                    \
        a0 = fmaf(e[4], bl[4], a0); a1 = fmaf(e[5], bl[5], a1);                    \
        a2 = fmaf(e[6], bl[6], a2); a3 = fmaf(e[7], bl[7], a3);                    \
        const float s = dpp_sum64((a0 + a1) + (a2 + a3));                          \
        const float A = frcp(s);                                                   \
        if (lane == 0) SL[wb + (ridx)] = s;                                        \
        _Pragma("unroll")                                                          \
        for (int k = 0; k < 8; ++k) ca[k] = fmaf(e[k], A, ca[k]);                  \
    }

    // ---------------- passes 1..9: rows 0..6 from LDS, 7..31 depth-4 global ----------------
    for (int it = 1; it < 10; ++it) {
        float bl[8];
        #pragma unroll
        for (int k = 0; k < 8; ++k) bl[k] = Bf[8 * lane + k];
        float ca[8] = {0.f,0.f,0.f,0.f,0.f,0.f,0.f,0.f};

        // LDS-resident rows 0..6 (V0/V1 ping-pong, row order preserved)
        {
            int4 V0 = LDL(0), V1 = LDL(1);
            STEP1(0, V0); V0 = LDL(2);
            STEP1(1, V1); V1 = LDL(3);
            STEP1(2, V0); V0 = LDL(4);
            STEP1(3, V1); V1 = LDL(5);
            STEP1(4, V0); V0 = LDL(6);
            STEP1(5, V1);
            STEP1(6, V0);
        }

        // global rows 7..26 (5 groups of 4), loads run 4 rows ahead
        #pragma unroll 1
        for (int g = 0; g < 20; g += 4) {
            STEP1(7 + g,  W0); W0 = LD(11 + g);
            STEP1(8 + g,  W1); W1 = LD(12 + g);
            STEP1(9 + g,  W2); W2 = LD(13 + g);
            STEP1(10 + g, W3); W3 = LD(14 + g);
        }
        // tail rows 27..31; reloads wrap to next pass's rows 7..10
        STEP1(27, W0); W0 = LD(31);
        STEP1(28, W1); W1 = LD(8);
        STEP1(29, W2); W2 = LD(9);
        STEP1(30, W3); W3 = LD(10);
        STEP1(31, W0); W0 = LD(7);

        const int cbase = (lane < 32) ? lane * 9 : 288 + (lane - 32) * 9;
        #pragma unroll
        for (int k = 0; k < 8; ++k) cred[wave][cbase + k] = ca[k];
        __syncthreads();
        if (tid < BN) {
            const int ci = credIdx(tid);
            float s = 0.f;
            #pragma unroll
            for (int wv = 0; wv < NW; ++wv) s += cred[wv][ci];
            Bf[tid] = frcp(s);
        }
        __syncthreads();
    }

    // ---------------- final: out = M * A_i * B_j (M from LDS for local rows) ----------------
    {
        float bf[8];
        #pragma unroll
        for (int k = 0; k < 8; ++k) bf[k] = Bf[8 * lane + k];

        auto emit_row = [&](int j) {
            const int lr = j & 31;
            const int4 w = (lr < LR)
                ? *reinterpret_cast<const int4*>(&Mlds[((j >> 5) * LR + lr) * BN + lane * 8])
                : *reinterpret_cast<const int4*>(Mb + (size_t)j * BN + lane * 8);
            float e[8];
            unpack2((unsigned)w.x, e[0], e[1]); unpack2((unsigned)w.y, e[2], e[3]);
            unpack2((unsigned)w.z, e[4], e[5]); unpack2((unsigned)w.w, e[6], e[7]);
            const float A = frcp(SL[j]);
            float4 o0, o1;
            o0.x = e[0] * A * bf[0]; o0.y = e[1] * A * bf[1];
            o0.z = e[2] * A * bf[2]; o0.w = e[3] * A * bf[3];
            o1.x = e[4] * A * bf[4]; o1.y = e[5] * A * bf[5];
            o1.z = e[6] * A * bf[6]; o1.w = e[7] * A * bf[7];
            *reinterpret_cast<float4*>(Ob + (size_t)j * BN + 4 * lane) = o0;
            *reinterpret_cast<float4*>(Ob + (size_t)j * BN + 256 + 4 * lane) = o1;
        };

        if (use_ws) {
            #pragma unroll 2
            for (int r = 0; r < RPW; ++r) emit_row(wb + r);
        } else {
            // M aliases out: descending power-of-2 ranges; fp32 write of row j clobbers
            // M rows 2j,2j+1, always in an already-consumed (higher) range.
            // (LDS-resident rows are immune to the aliasing entirely.)
            for (int L = 256; L >= 1; L >>= 1) {
                for (int j = L + wave; j < 2 * L; j += NW) emit_row(j);
                __syncthreads();
            }
            if (wave == 0) emit_row(0);
        }
    }
#undef LD
#undef LDL
#undef STEP1
}

extern "C" void kernel_launch(void* const* d_in, const int* in_sizes, int n_in,
                              void* d_out, int out_size, void* d_ws, size_t ws_size,
                              hipStream_t stream) {
    const float* logits = (const float*)d_in[0];
    float* out = (float*)d_out;
    const int B = in_sizes[0] / (BN * BN);   // 256
    const size_t need = (size_t)B * BN * BN * sizeof(unsigned short);  // 128 MB
    const int use_ws = (ws_size >= need) ? 1 : 0;
    hipLaunchKernelGGL(sinkhorn_fused, dim3(B), dim3(1024), 0, stream,
                       logits, out, (unsigned short*)d_ws, use_ws);
}